// Round 21
// baseline (315.267 us; speedup 1.0000x reference)
//
#include <hip/hip_runtime.h>

#define VQ_B 32
#define VQ_D 64
#define VQ_L 4096
#define VQ_N 1024
#define VQ_R (VQ_B * VQ_L)            /* 131072 rows */
#define VQ_ZQ ((size_t)VQ_R * VQ_D)   /* 8388608 z_q elements */
#define MAIN_BLOCK 256
#define MAIN_GRID (VQ_R / MAIN_BLOCK) /* 512 */
#define EPSREL 2.0e-3f                /* > 2^-9 RNE bf16 unit roundoff */
#define MRG_ABS 1e-4f                 /* reorder + quant + fp32-accum slack */
#define RT 2                          /* row-tiles per wave (32 rows) */
#define NSEG 4                        /* code segments (grid.y) */
#define SEGC (VQ_N / NSEG)            /* 256 codes per segment */
#define NCT (SEGC / 16)               /* 16 code-tiles per segment */
#define CAP_SEG 4                     /* candidate slots per (row, segment) */
#define KEYQ 0xFFFFFC00u              /* g-key quantization mask (10 code bits) */
#define OV_WAVES 4096                 /* overflow kernel: 1024 blk x 4 waves */

typedef __attribute__((ext_vector_type(16))) float f32x16;
typedef __attribute__((ext_vector_type(8)))  short short8;   /* 8 bf16 */
typedef __attribute__((ext_vector_type(4)))  float f32x4;
typedef __attribute__((ext_vector_type(4)))  unsigned int u32x4;

/* ---------- monotone float<->u32 keys ---------- */
__device__ __forceinline__ unsigned fmono(float x) {
    unsigned u = __builtin_bit_cast(unsigned, x);
    return (u & 0x80000000u) ? ~u : (u | 0x80000000u);
}
__device__ __forceinline__ float fmono_dec(unsigned k) {
    unsigned u = (k & 0x80000000u) ? (k & 0x7FFFFFFFu) : ~k;
    return __builtin_bit_cast(float, u);
}
__device__ __forceinline__ unsigned short f2bf(float x) {
    __bf16 h = (__bf16)x;  /* RNE */
    return __builtin_bit_cast(unsigned short, h);
}

/* ---------- validated numpy-pairwise norm machinery ---------- */
#define ZVE(i) ((i) < 16 ? zvA[(i) & 15] : (i) < 32 ? zvB[(i) & 15] \
               : (i) < 48 ? zvC[(i) & 15] : zvD[(i) & 15])
#define SQB(x) ({ float s_ = (x) * (x); asm volatile("" : "+v"(s_)); s_; })
#define NP_PAIRWISE64_SQ(dst)                                                  \
    do {                                                                       \
        float r0 = SQB(ZVE(0)), r1 = SQB(ZVE(1)), r2 = SQB(ZVE(2)),            \
              r3 = SQB(ZVE(3)), r4 = SQB(ZVE(4)), r5 = SQB(ZVE(5)),            \
              r6 = SQB(ZVE(6)), r7 = SQB(ZVE(7));                              \
        _Pragma("unroll")                                                      \
        for (int i_ = 1; i_ < 8; ++i_) {                                       \
            r0 += SQB(ZVE(8 * i_ + 0)); r1 += SQB(ZVE(8 * i_ + 1));            \
            r2 += SQB(ZVE(8 * i_ + 2)); r3 += SQB(ZVE(8 * i_ + 3));            \
            r4 += SQB(ZVE(8 * i_ + 4)); r5 += SQB(ZVE(8 * i_ + 5));            \
            r6 += SQB(ZVE(8 * i_ + 6)); r7 += SQB(ZVE(8 * i_ + 7));            \
        }                                                                      \
        dst = ((r0 + r1) + (r2 + r3)) + ((r4 + r5) + (r6 + r7));               \
    } while (0)

/* szz for one row from strided z (numpy 8-acc order, squares pre-rounded) */
#define NP_SZZ_FROM_ZP(szz_out)                                                \
    do {                                                                       \
        float a8_[8];                                                          \
        _Pragma("unroll")                                                      \
        for (int j_ = 0; j_ < 8; ++j_) {                                       \
            const float v_ = zp[(size_t)j_ << 12];                             \
            float s_ = v_ * v_;                                                \
            asm volatile("" : "+v"(s_));                                       \
            a8_[j_] = s_;                                                      \
        }                                                                      \
        _Pragma("unroll")                                                      \
        for (int i_ = 1; i_ < 8; ++i_) {                                       \
            _Pragma("unroll")                                                  \
            for (int j_ = 0; j_ < 8; ++j_) {                                   \
                const float v_ = zp[(size_t)(8 * i_ + j_) << 12];              \
                float s_ = v_ * v_;                                            \
                asm volatile("" : "+v"(s_));                                   \
                a8_[j_] += s_;                                                 \
            }                                                                  \
        }                                                                      \
        szz_out = ((a8_[0] + a8_[1]) + (a8_[2] + a8_[3]))                      \
                + ((a8_[4] + a8_[5]) + (a8_[6] + a8_[7]));                     \
    } while (0)

/* ---------- prep emb: exact nE (np chain), emb -> bf16(-2e), nEmax ---------- */
__global__ void vq_prep_emb(const float* __restrict__ emb, float* __restrict__ nE,
                            unsigned short* __restrict__ emb_bf,
                            unsigned* __restrict__ nEmax) {
    const int c = blockIdx.x * blockDim.x + threadIdx.x;
    if (c >= VQ_N) return;
    const float* ec = emb + (c << 6);
    f32x16 zvA, zvB, zvC, zvD;
#pragma unroll
    for (int d = 0; d < 16; ++d) {
        zvA[d] = ec[d];
        zvB[d] = ec[d + 16];
        zvC[d] = ec[d + 32];
        zvD[d] = ec[d + 48];
    }
    float s;
    NP_PAIRWISE64_SQ(s);
    nE[c] = s;
    atomicMax(nEmax, fmono(s));
#pragma unroll
    for (int d = 0; d < 64; ++d) emb_bf[(c << 6) + d] = f2bf(-2.0f * ec[d]);
}

/* ---------- prep z: bf16 rows + per-row margin ---------- */
__global__ __launch_bounds__(256) void vq_prep_z(
    const float* __restrict__ z, const unsigned* __restrict__ nEmax,
    unsigned short* __restrict__ z_bf, float* __restrict__ mrg) {
    const int r = blockIdx.x * 256 + threadIdx.x;
    const int b = r >> 12;
    const int l = r & (VQ_L - 1);
    const float* zp = z + ((size_t)b << 18) + l;
    unsigned short* o = z_bf + ((size_t)r << 6);
    float s = 0.0f;
#pragma unroll
    for (int j8 = 0; j8 < 8; ++j8) {
        unsigned w[4];
#pragma unroll
        for (int p = 0; p < 4; ++p) {
            const float v0 = zp[(size_t)(j8 * 8 + 2 * p) << 12];
            const float v1 = zp[(size_t)(j8 * 8 + 2 * p + 1) << 12];
            s = __builtin_fmaf(v0, v0, s);
            s = __builtin_fmaf(v1, v1, s);
            w[p] = (unsigned)f2bf(v0) | ((unsigned)f2bf(v1) << 16);
        }
        *(u32x4*)(o + j8 * 8) = (u32x4){w[0], w[1], w[2], w[3]};
    }
    const float nem = fmono_dec(*nEmax);
    mrg[r] = 8.0f * EPSREL * sqrtf(s * nem) + MRG_ABS;
}

/* ---------- two-sweep MFMA screen, ATOMIC-FREE emission ----------
   R20 lesson: blocking atomicAdd per emission (~1.3M x ~500cyc stalls) +
   cross-XCD candrow line ping-pong (WRITE 65 MB) dominated the screen.
   Fix: per (row,seg) all emissions come from ONE wave, so sweep B uses
   __ballot + group-popcount compaction with a per-(t,reg) running base
   in registers: deterministic positions (ascending code order), zero
   atomics, segment-private candseg[seg][row][CAP_SEG] written once.
   segcnt[row][seg] (u16) written once by lane cl==0. NSEG=4 halves the
   forced candidate count vs R20. LDS 33 KB w/ validated XOR swizzle
   (conflicts=0). Split accumulators (p,q) halve the MFMA chain; sweeps
   A and B use identical instruction sequences -> bit-identical g.
   Local-margin rigor unchanged: the true exact argmin is always within
   its own segment's (min + mrg) window, so it is always emitted. */
__global__ __launch_bounds__(256, 2) void vq_screen(
    const unsigned short* __restrict__ z_bf, const unsigned short* __restrict__ emb_bf,
    const float* __restrict__ nE, const float* __restrict__ mrg,
    unsigned short* __restrict__ segcnt, unsigned* __restrict__ candseg) {
    __shared__ unsigned short ebS[8 * SEGC * 8];  /* 32 KB, chunk-major+swz */
    __shared__ float neS[SEGC];                   /* 1 KB */
    const int tid = threadIdx.x;
    const int seg = blockIdx.y;
    const int c0 = seg * SEGC;                    /* block-uniform -> scalar */

    for (int q = tid; q < SEGC * 8; q += 256) {
        const short8 v = *(const short8*)(emb_bf + ((size_t)c0 << 6) + q * 8);
        const int chunk = q & 7, line = q >> 3;
        *(short8*)(ebS + (chunk * SEGC + (line ^ chunk)) * 8) = v;
    }
    neS[tid] = nE[c0 + tid];
    __syncthreads();

    const int w = tid >> 6, lane = tid & 63;
    const int cl = lane & 15, grp = lane >> 4;
    const int rowbase = blockIdx.x * (64 * RT) + w * (16 * RT);

    short8 a0[RT], a1[RT];
#pragma unroll
    for (int t = 0; t < RT; ++t) {
        const unsigned short* za = z_bf + ((size_t)(rowbase + t * 16 + cl) << 6) + grp * 8;
        a0[t] = *(const short8*)(za);
        a1[t] = *(const short8*)(za + 32);
    }

    int row_r[RT][4];
#pragma unroll
    for (int t = 0; t < RT; ++t)
#pragma unroll
        for (int reg = 0; reg < 4; ++reg)
            row_r[t][reg] = rowbase + t * 16 + grp * 4 + reg;

    float mt[RT][4];
#pragma unroll
    for (int t = 0; t < RT; ++t)
#pragma unroll
        for (int reg = 0; reg < 4; ++reg) mt[t][reg] = __builtin_inff();

    const f32x4 zr4 = (f32x4){0.0f, 0.0f, 0.0f, 0.0f};

    /* ---- sweep A: per-row min over this segment's codes ---- */
#pragma unroll 2
    for (int ct = 0; ct < NCT; ++ct) {
        const int cr = ct * 16 + cl;
        const short8 b0 = *(const short8*)(ebS + (grp * SEGC + (cr ^ grp)) * 8);
        const short8 b1 = *(const short8*)(ebS + ((grp + 4) * SEGC + (cr ^ (grp + 4))) * 8);
        const float ne = neS[cr];
        const f32x4 ne4 = (f32x4){ne, ne, ne, ne};
#pragma unroll
        for (int t = 0; t < RT; ++t) {
            const f32x4 p = __builtin_amdgcn_mfma_f32_16x16x32_bf16(a0[t], b0, ne4, 0, 0, 0);
            const f32x4 q = __builtin_amdgcn_mfma_f32_16x16x32_bf16(a1[t], b1, zr4, 0, 0, 0);
#pragma unroll
            for (int reg = 0; reg < 4; ++reg)
                mt[t][reg] = fminf(mt[t][reg], p[reg] + q[reg]);
        }
    }

    /* ---- allreduce across cl lanes, thr = min + mrg (in-place) ---- */
#pragma unroll
    for (int t = 0; t < RT; ++t)
#pragma unroll
        for (int reg = 0; reg < 4; ++reg) {
            float v = mt[t][reg];
            v = fminf(v, __shfl_xor(v, 1));
            v = fminf(v, __shfl_xor(v, 2));
            v = fminf(v, __shfl_xor(v, 4));
            v = fminf(v, __shfl_xor(v, 8));
            mt[t][reg] = v + mrg[row_r[t][reg]];
        }

    /* ---- sweep B: identical g bits; ballot-compacted emission ---- */
    int base[RT][4];
#pragma unroll
    for (int t = 0; t < RT; ++t)
#pragma unroll
        for (int reg = 0; reg < 4; ++reg) base[t][reg] = 0;

#pragma unroll 2
    for (int ct = 0; ct < NCT; ++ct) {
        const int cr = ct * 16 + cl;
        const short8 b0 = *(const short8*)(ebS + (grp * SEGC + (cr ^ grp)) * 8);
        const short8 b1 = *(const short8*)(ebS + ((grp + 4) * SEGC + (cr ^ (grp + 4))) * 8);
        const float ne = neS[cr];
        const f32x4 ne4 = (f32x4){ne, ne, ne, ne};
#pragma unroll
        for (int t = 0; t < RT; ++t) {
            const f32x4 p = __builtin_amdgcn_mfma_f32_16x16x32_bf16(a0[t], b0, ne4, 0, 0, 0);
            const f32x4 q = __builtin_amdgcn_mfma_f32_16x16x32_bf16(a1[t], b1, zr4, 0, 0, 0);
#pragma unroll
            for (int reg = 0; reg < 4; ++reg) {
                const float g = p[reg] + q[reg];
                const bool hit = (g <= mt[t][reg]);
                const unsigned long long bal = __ballot(hit);
                const unsigned gm = (unsigned)((bal >> (grp * 16)) & 0xFFFFull);
                if (hit) {
                    const int pos = base[t][reg]
                                  + __builtin_popcount(gm & ((1u << cl) - 1u));
                    if (pos < CAP_SEG)
                        candseg[((size_t)seg * VQ_R + row_r[t][reg]) * CAP_SEG + pos] =
                            (fmono(g) & KEYQ) | (unsigned)(c0 + cr);
                }
                base[t][reg] += __builtin_popcount(gm);
            }
        }
    }

    /* one plain u16 store per (row, seg) — no atomics anywhere */
    if (cl == 0) {
#pragma unroll
        for (int t = 0; t < RT; ++t)
#pragma unroll
            for (int reg = 0; reg < 4; ++reg)
                segcnt[(size_t)row_r[t][reg] * NSEG + seg] =
                    (unsigned short)base[t][reg];
    }
}

/* ---------- exact phase: prune by g-key, exact D on survivors ----------
   Overflow rows (any segment cnt > CAP_SEG) deferred to vq_overflow. */
__global__ __launch_bounds__(MAIN_BLOCK) void vq_exact(
    const float* __restrict__ z, const float* __restrict__ emb,
    const float* __restrict__ nE, const float* __restrict__ mrg,
    const unsigned short* __restrict__ segcnt, const unsigned* __restrict__ candseg,
    unsigned* __restrict__ ovl, unsigned* __restrict__ ovcnt,
    float* __restrict__ out, float* __restrict__ partials) {
    const int r = blockIdx.x * MAIN_BLOCK + threadIdx.x;
    const int b = r >> 12;
    const int l = r & (VQ_L - 1);
    const float* zp = z + ((size_t)b << 18) + l;

    float lsum = 0.0f;
    const unsigned long long cnts = *(const unsigned long long*)(segcnt + (size_t)r * NSEG);
    unsigned cs[NSEG];
    bool ovf = false;
#pragma unroll
    for (int s = 0; s < NSEG; ++s) {
        cs[s] = (unsigned)((cnts >> (16 * s)) & 0xFFFFull);
        ovf = ovf || (cs[s] > (unsigned)CAP_SEG);
    }

    if (!ovf) {
        float szz;
        NP_SZZ_FROM_ZP(szz);

        /* pass 1: min quantized g-key over the 4 segment lists */
        unsigned kmin = 0xFFFFFFFFu;
#pragma unroll
        for (int s = 0; s < NSEG; ++s)
            for (unsigned i = 0; i < cs[s]; ++i) {
                const unsigned key = candseg[((size_t)s * VQ_R + r) * CAP_SEG + i];
                kmin = (key < kmin) ? key : kmin;
            }
        const float gthr = fmono_dec(kmin & KEYQ) + mrg[r];

        /* pass 2: exact D only for pruned survivors (~1.3/row) */
        unsigned long long best = ~0ull;
#pragma unroll
        for (int s = 0; s < NSEG; ++s)
            for (unsigned i = 0; i < cs[s]; ++i) {
                const unsigned key = candseg[((size_t)s * VQ_R + r) * CAP_SEG + i];
                if (fmono_dec(key & KEYQ) > gthr) continue;
                const int c = (int)(key & 1023u);
                const float* __restrict__ ec = emb + (c << 6);
                float acc = 0.0f;
#pragma unroll
                for (int k = 0; k < VQ_D; ++k)
                    acc = __builtin_fmaf(zp[(size_t)k << 12], ec[k], acc);
                const float D = (szz - 2.0f * acc) + nE[c];
                const unsigned long long bk =
                    ((unsigned long long)fmono(D) << 32) | (unsigned)c;
                best = (bk < best) ? bk : best;
            }
        const int bc = (int)(best & 1023u);

        const float* __restrict__ eb = emb + (bc << 6);
#pragma unroll
        for (int d = 0; d < VQ_D; ++d) {
            const float q = eb[d];
            const float zd = zp[(size_t)d << 12];
            out[((size_t)b << 18) + ((size_t)d << 12) + l] = q;
            const float df = q - zd;
            lsum = __builtin_fmaf(df, df, lsum);
        }
        out[VQ_ZQ + 1 + (size_t)r] = (float)bc;
    } else {
        ovl[atomicAdd(ovcnt, 1u)] = (unsigned)r;
    }

#pragma unroll
    for (int off = 32; off > 0; off >>= 1)
        lsum += __shfl_down(lsum, off, 64);
    __shared__ float wsum[MAIN_BLOCK / 64];
    const int lane = threadIdx.x & 63;
    const int wid = threadIdx.x >> 6;
    if (lane == 0) wsum[wid] = lsum;
    __syncthreads();
    if (threadIdx.x == 0)
        partials[blockIdx.x] = (wsum[0] + wsum[1]) + (wsum[2] + wsum[3]);
}

/* ---------- overflow: one WAVE per deferred row, exact full scan ---------- */
__global__ __launch_bounds__(256) void vq_overflow(
    const float* __restrict__ z, const float* __restrict__ emb,
    const float* __restrict__ nE, const unsigned* __restrict__ ovl,
    const unsigned* __restrict__ ovcnt, float* __restrict__ out,
    float* __restrict__ ovloss) {
    const int gw = (blockIdx.x * 256 + threadIdx.x) >> 6;  /* global wave id */
    const int lane = threadIdx.x & 63;
    const unsigned n = *ovcnt;
    for (unsigned i = gw; i < n; i += OV_WAVES) {
        const int r = (int)ovl[i];
        const int b = r >> 12;
        const int l = r & (VQ_L - 1);
        const float* zp = z + ((size_t)b << 18) + l;

        float szz;
        NP_SZZ_FROM_ZP(szz);   /* all lanes same row -> broadcast loads */

        unsigned long long best = ~0ull;
        for (int j = 0; j < 16; ++j) {
            const int c = lane * 16 + j;
            const float* __restrict__ ec = emb + (c << 6);
            float acc = 0.0f;
#pragma unroll
            for (int k = 0; k < VQ_D; ++k)
                acc = __builtin_fmaf(zp[(size_t)k << 12], ec[k], acc);
            const float D = (szz - 2.0f * acc) + nE[c];
            const unsigned long long bk = ((unsigned long long)fmono(D) << 32) | (unsigned)c;
            best = (bk < best) ? bk : best;
        }
#pragma unroll
        for (int off = 32; off > 0; off >>= 1) {
            const unsigned long long o = __shfl_xor(best, off, 64);
            best = (o < best) ? o : best;
        }
        const int bc = (int)(best & 1023u);

        const float q = emb[(bc << 6) + lane];
        const float zd = zp[(size_t)lane << 12];
        out[((size_t)b << 18) + ((size_t)lane << 12) + l] = q;
        const float df = q - zd;
        float ls = df * df;
#pragma unroll
        for (int off = 32; off > 0; off >>= 1)
            ls += __shfl_down(ls, off, 64);
        if (lane == 0) {
            out[VQ_ZQ + 1 + (size_t)r] = (float)bc;
            atomicAdd(ovloss, ls);
        }
    }
}

__global__ void vq_final(const float* __restrict__ partials,
                         const float* __restrict__ ovloss, float* __restrict__ out) {
    if (threadIdx.x == 0 && blockIdx.x == 0) {
        float s = 0.0f;
        for (int i = 0; i < MAIN_GRID; ++i) s += partials[i];
        s += *ovloss;
        const float mse = s / (float)VQ_ZQ;
        out[VQ_ZQ] = mse + 0.25f * mse;
    }
}

/* ================= fallback path (round-8, validated, ~335us) ========== */
__global__ void vq_norme_fb(const float* __restrict__ emb, float* __restrict__ nEf) {
    const int c = blockIdx.x * blockDim.x + threadIdx.x;
    if (c >= VQ_N) return;
    const float* ec = emb + (c << 6);
    f32x16 zvA, zvB, zvC, zvD;
#pragma unroll
    for (int d = 0; d < 16; ++d) {
        zvA[d] = ec[d]; zvB[d] = ec[d + 16]; zvC[d] = ec[d + 32]; zvD[d] = ec[d + 48];
    }
    float s;
    NP_PAIRWISE64_SQ(s);
    nEf[c] = s;
}
__global__ __launch_bounds__(256, 4) void vq_dist_fb(
    const float* __restrict__ z, const float* __restrict__ emb,
    const float* __restrict__ nEf, float2* __restrict__ cand) {
    __shared__ float zs[VQ_D * 64];
    const int w = threadIdx.x >> 6;
    const int lane = threadIdx.x & 63;
    const int r = blockIdx.x * 64 + lane;
    const int b = r >> 12;
    const int l = r & (VQ_L - 1);
    const float* zp = z + ((size_t)b << 18) + l;
#pragma unroll
    for (int j = 0; j < 16; ++j) {
        const int d = (w << 4) + j;
        zs[d * 64 + lane] = zp[(size_t)d << 12];
    }
    __syncthreads();
    float a8[8];
#pragma unroll
    for (int j = 0; j < 8; ++j) {
        const float v = zs[j * 64 + lane];
        float s = v * v; asm volatile("" : "+v"(s)); a8[j] = s;
    }
#pragma unroll
    for (int i = 1; i < 8; ++i) {
#pragma unroll
        for (int j = 0; j < 8; ++j) {
            const float v = zs[(8 * i + j) * 64 + lane];
            float s = v * v; asm volatile("" : "+v"(s)); a8[j] += s;
        }
    }
    const float szz = ((a8[0] + a8[1]) + (a8[2] + a8[3])) + ((a8[4] + a8[5]) + (a8[6] + a8[7]));
    const int c0 = __builtin_amdgcn_readfirstlane(w) * 256;
    float best = __builtin_inff();
    int bc = c0;
    for (int t = 0; t < 256; t += 16) {
        float acc[16];
#pragma unroll
        for (int j = 0; j < 16; ++j) acc[j] = 0.0f;
#pragma unroll
        for (int kk = 0; kk < VQ_D; kk += 4) {
            const float z0 = zs[(kk + 0) * 64 + lane];
            const float z1 = zs[(kk + 1) * 64 + lane];
            const float z2 = zs[(kk + 2) * 64 + lane];
            const float z3 = zs[(kk + 3) * 64 + lane];
#pragma unroll
            for (int j = 0; j < 16; ++j) {
                const float* __restrict__ ec = emb + ((c0 + t + j) << 6) + kk;
                acc[j] = __builtin_fmaf(z0, ec[0], acc[j]);
                acc[j] = __builtin_fmaf(z1, ec[1], acc[j]);
                acc[j] = __builtin_fmaf(z2, ec[2], acc[j]);
                acc[j] = __builtin_fmaf(z3, ec[3], acc[j]);
            }
        }
#pragma unroll
        for (int j = 0; j < 16; ++j) {
            const int c = c0 + t + j;
            const float dist = (szz - 2.0f * acc[j]) + nEf[c];
            if (dist < best) { best = dist; bc = c; }
        }
    }
    cand[(size_t)w * VQ_R + r] = make_float2(best, (float)bc);
}
__global__ __launch_bounds__(MAIN_BLOCK) void vq_epilogue_fb(
    const float* __restrict__ z, const float* __restrict__ emb,
    const float2* __restrict__ cand, float* __restrict__ out,
    float* __restrict__ partials) {
    const int r = blockIdx.x * MAIN_BLOCK + threadIdx.x;
    const int b = r >> 12;
    const int l = r & (VQ_L - 1);
    float best = __builtin_inff();
    int bc = 0;
#pragma unroll
    for (int seg = 0; seg < 4; ++seg) {
        const float2 cd = cand[(size_t)seg * VQ_R + r];
        if (cd.x < best) { best = cd.x; bc = (int)cd.y; }
    }
    const float* zp = z + ((size_t)b << 18) + l;
    const float* __restrict__ eb = emb + (bc << 6);
    float lsum = 0.0f;
#pragma unroll
    for (int d = 0; d < VQ_D; ++d) {
        const float q = eb[d];
        const float zd = zp[(size_t)d << 12];
        out[((size_t)b << 18) + ((size_t)d << 12) + l] = q;
        const float df = q - zd;
        lsum = __builtin_fmaf(df, df, lsum);
    }
    out[VQ_ZQ + 1 + (size_t)r] = (float)bc;
#pragma unroll
    for (int off = 32; off > 0; off >>= 1)
        lsum += __shfl_down(lsum, off, 64);
    __shared__ float wsum[MAIN_BLOCK / 64];
    const int lane = threadIdx.x & 63;
    const int wid = threadIdx.x >> 6;
    if (lane == 0) wsum[wid] = lsum;
    __syncthreads();
    if (threadIdx.x == 0)
        partials[blockIdx.x] = (wsum[0] + wsum[1]) + (wsum[2] + wsum[3]);
}
__global__ void vq_final_fb(const float* __restrict__ partials, float* __restrict__ out) {
    if (threadIdx.x == 0 && blockIdx.x == 0) {
        float s = 0.0f;
        for (int i = 0; i < MAIN_GRID; ++i) s += partials[i];
        const float mse = s / (float)VQ_ZQ;
        out[VQ_ZQ] = mse + 0.25f * mse;
    }
}

/* ================= launch ================= */
extern "C" void kernel_launch(void* const* d_in, const int* in_sizes, int n_in,
                              void* d_out, int out_size, void* d_ws, size_t ws_size,
                              hipStream_t stream) {
    const float* z   = (const float*)d_in[0];
    const float* emb = (const float*)d_in[1];
    float* out = (float*)d_out;
    char* ws = (char*)d_ws;

    /* layout (16B-aligned); ovl overlays z_bf (z_bf dead after vq_screen) */
    unsigned short* z_bf   = (unsigned short*)(ws);                       /* 16777216 B */
    unsigned*       ovl    = (unsigned*)(ws);                             /* overlay    */
    unsigned short* emb_bf = (unsigned short*)(ws + 16777216);            /*   131072 B */
    unsigned*       candsg = (unsigned*)(ws + 16908288);                  /*  8388608 B */
    unsigned short* segcnt = (unsigned short*)(ws + 25296896);            /*  1048576 B */
    float*          mrg    = (float*)(ws + 26345472);                     /*   524288 B */
    float*          nE     = (float*)(ws + 26869760);                     /*     4096 B */
    float*          parts  = (float*)(ws + 26873856);                     /*     2048 B */
    unsigned*       nEmax  = (unsigned*)(ws + 26875904);                  /*        4 B */
    unsigned*       ovcnt  = (unsigned*)(ws + 26875908);                  /*        4 B */
    float*          ovloss = (float*)(ws + 26875912);                     /*        4 B */
    const size_t need = 26875968;  /* same footprint as validated R17-R20 */

    if (ws_size >= need) {
        hipMemsetAsync(nEmax, 0, 12, stream);  /* nEmax, ovcnt, ovloss */
        vq_prep_emb<<<dim3(4), dim3(256), 0, stream>>>(emb, nE, emb_bf, nEmax);
        vq_prep_z<<<dim3(512), dim3(256), 0, stream>>>(z, nEmax, z_bf, mrg);
        vq_screen<<<dim3(VQ_R / (64 * RT), NSEG), dim3(256), 0, stream>>>(
            z_bf, emb_bf, nE, mrg, segcnt, candsg);
        vq_exact<<<dim3(MAIN_GRID), dim3(MAIN_BLOCK), 0, stream>>>(
            z, emb, nE, mrg, segcnt, candsg, ovl, ovcnt, out, parts);
        vq_overflow<<<dim3(OV_WAVES / 4), dim3(256), 0, stream>>>(
            z, emb, nE, ovl, ovcnt, out, ovloss);
        vq_final<<<dim3(1), dim3(64), 0, stream>>>(parts, ovloss, out);
    } else {
        /* validated round-8 fallback (~4.2 MB ws) */
        float* nEf = (float*)ws;
        float* partials = nEf + VQ_N;
        float2* cand = (float2*)(partials + MAIN_GRID);
        vq_norme_fb<<<dim3(4), dim3(256), 0, stream>>>(emb, nEf);
        vq_dist_fb<<<dim3(VQ_R / 64), dim3(256), 0, stream>>>(z, emb, nEf, cand);
        vq_epilogue_fb<<<dim3(MAIN_GRID), dim3(MAIN_BLOCK), 0, stream>>>(z, emb, cand, out, partials);
        vq_final_fb<<<dim3(1), dim3(64), 0, stream>>>(partials, out);
    }
}

// Round 22
// 208.306 us; speedup vs baseline: 1.5135x; 1.5135x over previous
//
#include <hip/hip_runtime.h>

#define VQ_B 32
#define VQ_D 64
#define VQ_L 4096
#define VQ_N 1024
#define VQ_R (VQ_B * VQ_L)            /* 131072 rows */
#define VQ_ZQ ((size_t)VQ_R * VQ_D)   /* 8388608 z_q elements */
#define MAIN_BLOCK 256
#define MAIN_GRID (VQ_R / MAIN_BLOCK) /* 512 */
#define EPSREL 2.0e-3f                /* > 2^-9 RNE bf16 unit roundoff */
#define MRG_ABS 1e-4f                 /* reorder + quant + fp32-accum slack */
#define RT 2                          /* row-tiles per wave (32 rows) */
#define NSEG 4                        /* code segments */
#define SEGC (VQ_N / NSEG)            /* 256 codes per segment */
#define NCT (SEGC / 16)               /* 16 code-tiles per segment */
#define CAP_SEG 4                     /* candidate slots per (row, segment) */
#define KEYQ 0xFFFFFC00u              /* g-key quantization mask (10 code bits) */
#define OV_WAVES 4096                 /* overflow kernel: 1024 blk x 4 waves */
#define OVL_CAP (1u << 20)

typedef __attribute__((ext_vector_type(16))) float f32x16;
typedef __attribute__((ext_vector_type(8)))  short short8;   /* 8 bf16 */
typedef __attribute__((ext_vector_type(4)))  float f32x4;
typedef __attribute__((ext_vector_type(4)))  unsigned int u32x4;

/* ---------- monotone float<->u32 keys ---------- */
__device__ __forceinline__ unsigned fmono(float x) {
    unsigned u = __builtin_bit_cast(unsigned, x);
    return (u & 0x80000000u) ? ~u : (u | 0x80000000u);
}
__device__ __forceinline__ float fmono_dec(unsigned k) {
    unsigned u = (k & 0x80000000u) ? (k & 0x7FFFFFFFu) : ~k;
    return __builtin_bit_cast(float, u);
}
__device__ __forceinline__ unsigned short f2bf(float x) {
    __bf16 h = (__bf16)x;  /* RNE */
    return __builtin_bit_cast(unsigned short, h);
}

/* ---------- validated numpy-pairwise norm machinery ---------- */
#define ZVE(i) ((i) < 16 ? zvA[(i) & 15] : (i) < 32 ? zvB[(i) & 15] \
               : (i) < 48 ? zvC[(i) & 15] : zvD[(i) & 15])
#define SQB(x) ({ float s_ = (x) * (x); asm volatile("" : "+v"(s_)); s_; })
#define NP_PAIRWISE64_SQ(dst)                                                  \
    do {                                                                       \
        float r0 = SQB(ZVE(0)), r1 = SQB(ZVE(1)), r2 = SQB(ZVE(2)),            \
              r3 = SQB(ZVE(3)), r4 = SQB(ZVE(4)), r5 = SQB(ZVE(5)),            \
              r6 = SQB(ZVE(6)), r7 = SQB(ZVE(7));                              \
        _Pragma("unroll")                                                      \
        for (int i_ = 1; i_ < 8; ++i_) {                                       \
            r0 += SQB(ZVE(8 * i_ + 0)); r1 += SQB(ZVE(8 * i_ + 1));            \
            r2 += SQB(ZVE(8 * i_ + 2)); r3 += SQB(ZVE(8 * i_ + 3));            \
            r4 += SQB(ZVE(8 * i_ + 4)); r5 += SQB(ZVE(8 * i_ + 5));            \
            r6 += SQB(ZVE(8 * i_ + 6)); r7 += SQB(ZVE(8 * i_ + 7));            \
        }                                                                      \
        dst = ((r0 + r1) + (r2 + r3)) + ((r4 + r5) + (r6 + r7));               \
    } while (0)

/* szz for one row from strided z (numpy 8-acc order, squares pre-rounded) */
#define NP_SZZ_FROM_ZP(szz_out)                                                \
    do {                                                                       \
        float a8_[8];                                                          \
        _Pragma("unroll")                                                      \
        for (int j_ = 0; j_ < 8; ++j_) {                                       \
            const float v_ = zp[(size_t)j_ << 12];                             \
            float s_ = v_ * v_;                                                \
            asm volatile("" : "+v"(s_));                                       \
            a8_[j_] = s_;                                                      \
        }                                                                      \
        _Pragma("unroll")                                                      \
        for (int i_ = 1; i_ < 8; ++i_) {                                       \
            _Pragma("unroll")                                                  \
            for (int j_ = 0; j_ < 8; ++j_) {                                   \
                const float v_ = zp[(size_t)(8 * i_ + j_) << 12];              \
                float s_ = v_ * v_;                                            \
                asm volatile("" : "+v"(s_));                                   \
                a8_[j_] += s_;                                                 \
            }                                                                  \
        }                                                                      \
        szz_out = ((a8_[0] + a8_[1]) + (a8_[2] + a8_[3]))                      \
                + ((a8_[4] + a8_[5]) + (a8_[6] + a8_[7]));                     \
    } while (0)

/* ---------- prep emb: exact nE (np chain), emb -> bf16(-2e), nEmax ---------- */
__global__ void vq_prep_emb(const float* __restrict__ emb, float* __restrict__ nE,
                            unsigned short* __restrict__ emb_bf,
                            unsigned* __restrict__ nEmax) {
    const int c = blockIdx.x * blockDim.x + threadIdx.x;
    if (c >= VQ_N) return;
    const float* ec = emb + (c << 6);
    f32x16 zvA, zvB, zvC, zvD;
#pragma unroll
    for (int d = 0; d < 16; ++d) {
        zvA[d] = ec[d];
        zvB[d] = ec[d + 16];
        zvC[d] = ec[d + 32];
        zvD[d] = ec[d + 48];
    }
    float s;
    NP_PAIRWISE64_SQ(s);
    nE[c] = s;
    atomicMax(nEmax, fmono(s));
#pragma unroll
    for (int d = 0; d < 64; ++d) emb_bf[(c << 6) + d] = f2bf(-2.0f * ec[d]);
}

/* ---------- prep z: bf16 rows + per-row margin (for the screen) ---------- */
__global__ __launch_bounds__(256) void vq_prep_z(
    const float* __restrict__ z, const unsigned* __restrict__ nEmax,
    unsigned short* __restrict__ z_bf, float* __restrict__ mrg) {
    const int r = blockIdx.x * 256 + threadIdx.x;
    const int b = r >> 12;
    const int l = r & (VQ_L - 1);
    const float* zp = z + ((size_t)b << 18) + l;
    unsigned short* o = z_bf + ((size_t)r << 6);
    float s = 0.0f;
#pragma unroll
    for (int j8 = 0; j8 < 8; ++j8) {
        unsigned w[4];
#pragma unroll
        for (int p = 0; p < 4; ++p) {
            const float v0 = zp[(size_t)(j8 * 8 + 2 * p) << 12];
            const float v1 = zp[(size_t)(j8 * 8 + 2 * p + 1) << 12];
            s = __builtin_fmaf(v0, v0, s);
            s = __builtin_fmaf(v1, v1, s);
            w[p] = (unsigned)f2bf(v0) | ((unsigned)f2bf(v1) << 16);
        }
        *(u32x4*)(o + j8 * 8) = (u32x4){w[0], w[1], w[2], w[3]};
    }
    const float nem = fmono_dec(*nEmax);
    mrg[r] = 8.0f * EPSREL * sqrtf(s * nem) + MRG_ABS;
}

/* ---------- two-sweep MFMA screen, atomic-free ballot emission ----------
   (validated R21 structure, byte-identical) */
__global__ __launch_bounds__(256, 2) void vq_screen(
    const unsigned short* __restrict__ z_bf, const unsigned short* __restrict__ emb_bf,
    const float* __restrict__ nE, const float* __restrict__ mrg,
    unsigned short* __restrict__ segcnt, unsigned* __restrict__ candseg) {
    __shared__ unsigned short ebS[8 * SEGC * 8];  /* 32 KB, chunk-major+swz */
    __shared__ float neS[SEGC];                   /* 1 KB */
    const int tid = threadIdx.x;
    const int seg = blockIdx.y;
    const int c0 = seg * SEGC;                    /* block-uniform -> scalar */

    for (int q = tid; q < SEGC * 8; q += 256) {
        const short8 v = *(const short8*)(emb_bf + ((size_t)c0 << 6) + q * 8);
        const int chunk = q & 7, line = q >> 3;
        *(short8*)(ebS + (chunk * SEGC + (line ^ chunk)) * 8) = v;
    }
    neS[tid] = nE[c0 + tid];
    __syncthreads();

    const int w = tid >> 6, lane = tid & 63;
    const int cl = lane & 15, grp = lane >> 4;
    const int rowbase = blockIdx.x * (64 * RT) + w * (16 * RT);

    short8 a0[RT], a1[RT];
#pragma unroll
    for (int t = 0; t < RT; ++t) {
        const unsigned short* za = z_bf + ((size_t)(rowbase + t * 16 + cl) << 6) + grp * 8;
        a0[t] = *(const short8*)(za);
        a1[t] = *(const short8*)(za + 32);
    }

    int row_r[RT][4];
#pragma unroll
    for (int t = 0; t < RT; ++t)
#pragma unroll
        for (int reg = 0; reg < 4; ++reg)
            row_r[t][reg] = rowbase + t * 16 + grp * 4 + reg;

    float mt[RT][4];
#pragma unroll
    for (int t = 0; t < RT; ++t)
#pragma unroll
        for (int reg = 0; reg < 4; ++reg) mt[t][reg] = __builtin_inff();

    const f32x4 zr4 = (f32x4){0.0f, 0.0f, 0.0f, 0.0f};

    /* ---- sweep A: per-row min over this segment's codes ---- */
#pragma unroll 2
    for (int ct = 0; ct < NCT; ++ct) {
        const int cr = ct * 16 + cl;
        const short8 b0 = *(const short8*)(ebS + (grp * SEGC + (cr ^ grp)) * 8);
        const short8 b1 = *(const short8*)(ebS + ((grp + 4) * SEGC + (cr ^ (grp + 4))) * 8);
        const float ne = neS[cr];
        const f32x4 ne4 = (f32x4){ne, ne, ne, ne};
#pragma unroll
        for (int t = 0; t < RT; ++t) {
            const f32x4 p = __builtin_amdgcn_mfma_f32_16x16x32_bf16(a0[t], b0, ne4, 0, 0, 0);
            const f32x4 q = __builtin_amdgcn_mfma_f32_16x16x32_bf16(a1[t], b1, zr4, 0, 0, 0);
#pragma unroll
            for (int reg = 0; reg < 4; ++reg)
                mt[t][reg] = fminf(mt[t][reg], p[reg] + q[reg]);
        }
    }

    /* ---- allreduce across cl lanes, thr = min + mrg (in-place) ---- */
#pragma unroll
    for (int t = 0; t < RT; ++t)
#pragma unroll
        for (int reg = 0; reg < 4; ++reg) {
            float v = mt[t][reg];
            v = fminf(v, __shfl_xor(v, 1));
            v = fminf(v, __shfl_xor(v, 2));
            v = fminf(v, __shfl_xor(v, 4));
            v = fminf(v, __shfl_xor(v, 8));
            mt[t][reg] = v + mrg[row_r[t][reg]];
        }

    /* ---- sweep B: identical g bits; ballot-compacted emission ---- */
    int base[RT][4];
#pragma unroll
    for (int t = 0; t < RT; ++t)
#pragma unroll
        for (int reg = 0; reg < 4; ++reg) base[t][reg] = 0;

#pragma unroll 2
    for (int ct = 0; ct < NCT; ++ct) {
        const int cr = ct * 16 + cl;
        const short8 b0 = *(const short8*)(ebS + (grp * SEGC + (cr ^ grp)) * 8);
        const short8 b1 = *(const short8*)(ebS + ((grp + 4) * SEGC + (cr ^ (grp + 4))) * 8);
        const float ne = neS[cr];
        const f32x4 ne4 = (f32x4){ne, ne, ne, ne};
#pragma unroll
        for (int t = 0; t < RT; ++t) {
            const f32x4 p = __builtin_amdgcn_mfma_f32_16x16x32_bf16(a0[t], b0, ne4, 0, 0, 0);
            const f32x4 q = __builtin_amdgcn_mfma_f32_16x16x32_bf16(a1[t], b1, zr4, 0, 0, 0);
#pragma unroll
            for (int reg = 0; reg < 4; ++reg) {
                const float g = p[reg] + q[reg];
                const bool hit = (g <= mt[t][reg]);
                const unsigned long long bal = __ballot(hit);
                const unsigned gm = (unsigned)((bal >> (grp * 16)) & 0xFFFFull);
                if (hit) {
                    const int pos = base[t][reg]
                                  + __builtin_popcount(gm & ((1u << cl) - 1u));
                    if (pos < CAP_SEG)
                        candseg[((size_t)seg * VQ_R + row_r[t][reg]) * CAP_SEG + pos] =
                            (fmono(g) & KEYQ) | (unsigned)(c0 + cr);
                }
                base[t][reg] += __builtin_popcount(gm);
            }
        }
    }

    if (cl == 0) {
#pragma unroll
        for (int t = 0; t < RT; ++t)
#pragma unroll
            for (int reg = 0; reg < 4; ++reg)
                segcnt[(size_t)row_r[t][reg] * NSEG + seg] =
                    (unsigned short)base[t][reg];
    }
}

/* ---------- szz: per-row numpy-pairwise sum of squares (bit-exact) ---------- */
__global__ __launch_bounds__(256) void vq_szz(
    const float* __restrict__ z, float* __restrict__ szz_np) {
    const int r = blockIdx.x * 256 + threadIdx.x;
    const int b = r >> 12;
    const int l = r & (VQ_L - 1);
    const float* zp = z + ((size_t)b << 18) + l;
    float szz;
    NP_SZZ_FROM_ZP(szz);
    szz_np[r] = szz;
}

/* ---------- pickseg: one thread per (row, segment) ----------
   Exact D for EVERY candidate the segment emitted (superset of the
   margin window always contains the true argmin: it is emitted by its
   own segment, or that segment overflowed -> full-scan covers it).
   One fire-and-forget u64 atomicMin per thread (order-independent min,
   key = fmono(D)<<32|c -> strict-< first-index tie-break). 8192 waves
   (4x R21's exact) with a far shorter serial chain. */
__global__ __launch_bounds__(256) void vq_pickseg(
    const float* __restrict__ z, const float* __restrict__ emb,
    const float* __restrict__ nE, const float* __restrict__ szz_np,
    const unsigned short* __restrict__ segcnt, const unsigned* __restrict__ candseg,
    unsigned long long* __restrict__ dmin, unsigned* __restrict__ ovl,
    unsigned* __restrict__ ovcnt) {
    const int r = blockIdx.x * 256 + threadIdx.x;
    const int s = blockIdx.y;
    const unsigned cnt = segcnt[(size_t)r * NSEG + s];
    if (cnt > (unsigned)CAP_SEG) {
        const unsigned idx = atomicAdd(ovcnt, 1u);
        if (idx < OVL_CAP) ovl[idx] = (unsigned)r;   /* dup-tolerant */
        return;
    }
    const int b = r >> 12;
    const int l = r & (VQ_L - 1);
    const float* zp = z + ((size_t)b << 18) + l;
    const float szz = szz_np[r];

    unsigned long long best = ~0ull;
    for (unsigned i = 0; i < cnt; ++i) {
        const unsigned key = candseg[((size_t)s * VQ_R + r) * CAP_SEG + i];
        const int c = (int)(key & 1023u);
        const float* __restrict__ ec = emb + (c << 6);
        float acc = 0.0f;
#pragma unroll
        for (int k4 = 0; k4 < 16; ++k4) {            /* float4 loads, k ascending */
            const f32x4 e4 = *(const f32x4*)(ec + k4 * 4);
            acc = __builtin_fmaf(zp[(size_t)(k4 * 4 + 0) << 12], e4[0], acc);
            acc = __builtin_fmaf(zp[(size_t)(k4 * 4 + 1) << 12], e4[1], acc);
            acc = __builtin_fmaf(zp[(size_t)(k4 * 4 + 2) << 12], e4[2], acc);
            acc = __builtin_fmaf(zp[(size_t)(k4 * 4 + 3) << 12], e4[3], acc);
        }
        const float D = (szz - 2.0f * acc) + nE[c];
        const unsigned long long bk = ((unsigned long long)fmono(D) << 32) | (unsigned)c;
        best = (bk < best) ? bk : best;
    }
    if (best != ~0ull) atomicMin(dmin + r, best);    /* result unused: no stall */
}

/* ---------- overflow: one WAVE per deferred row, exact full scan ---------- */
__global__ __launch_bounds__(256) void vq_overflow(
    const float* __restrict__ z, const float* __restrict__ emb,
    const float* __restrict__ nE, const float* __restrict__ szz_np,
    const unsigned* __restrict__ ovl, const unsigned* __restrict__ ovcnt,
    unsigned long long* __restrict__ dmin) {
    const int gw = (blockIdx.x * 256 + threadIdx.x) >> 6;  /* global wave id */
    const int lane = threadIdx.x & 63;
    unsigned n = *ovcnt;
    if (n > OVL_CAP) n = OVL_CAP;
    for (unsigned i = gw; i < n; i += OV_WAVES) {
        const int r = (int)ovl[i];
        const int b = r >> 12;
        const int l = r & (VQ_L - 1);
        const float* zp = z + ((size_t)b << 18) + l;
        const float szz = szz_np[r];

        unsigned long long best = ~0ull;
        for (int j = 0; j < 16; ++j) {
            const int c = lane * 16 + j;
            const float* __restrict__ ec = emb + (c << 6);
            float acc = 0.0f;
#pragma unroll
            for (int k4 = 0; k4 < 16; ++k4) {
                const f32x4 e4 = *(const f32x4*)(ec + k4 * 4);
                acc = __builtin_fmaf(zp[(size_t)(k4 * 4 + 0) << 12], e4[0], acc);
                acc = __builtin_fmaf(zp[(size_t)(k4 * 4 + 1) << 12], e4[1], acc);
                acc = __builtin_fmaf(zp[(size_t)(k4 * 4 + 2) << 12], e4[2], acc);
                acc = __builtin_fmaf(zp[(size_t)(k4 * 4 + 3) << 12], e4[3], acc);
            }
            const float D = (szz - 2.0f * acc) + nE[c];
            const unsigned long long bk = ((unsigned long long)fmono(D) << 32) | (unsigned)c;
            best = (bk < best) ? bk : best;
        }
#pragma unroll
        for (int off = 32; off > 0; off >>= 1) {
            const unsigned long long o = __shfl_xor(best, off, 64);
            best = (o < best) ? o : best;
        }
        if (lane == 0) atomicMin(dmin + r, best);
    }
}

/* ---------- write: codes + z_q + deterministic loss partials ----------
   Grid (512, 4): 8192 waves, pure bandwidth. Block (gx, gy) handles 256
   rows x 16 d's. Loss reduced per block -> parts2 (candseg overlay,
   dead by now); summed in vq_final with a fixed tree: deterministic. */
__global__ __launch_bounds__(256) void vq_write(
    const float* __restrict__ z, const float* __restrict__ emb,
    const unsigned long long* __restrict__ dmin, float* __restrict__ out,
    float* __restrict__ parts2) {
    const int r = blockIdx.x * 256 + threadIdx.x;
    const int b = r >> 12;
    const int l = r & (VQ_L - 1);
    const int bc = (int)(dmin[r] & 1023u);
    if (blockIdx.y == 0) out[VQ_ZQ + 1 + (size_t)r] = (float)bc;

    const int d0 = blockIdx.y * 16;
    float lsum = 0.0f;
#pragma unroll
    for (int q4 = 0; q4 < 4; ++q4) {
        const f32x4 e4 = *(const f32x4*)(emb + (bc << 6) + d0 + q4 * 4);
#pragma unroll
        for (int j = 0; j < 4; ++j) {
            const int d = d0 + q4 * 4 + j;
            const size_t idx = ((size_t)b << 18) + ((size_t)d << 12) + l;
            const float zd = z[idx];
            out[idx] = e4[j];
            const float df = e4[j] - zd;
            lsum = __builtin_fmaf(df, df, lsum);
        }
    }
#pragma unroll
    for (int off = 32; off > 0; off >>= 1)
        lsum += __shfl_down(lsum, off, 64);
    __shared__ float wsum[4];
    const int lane = threadIdx.x & 63;
    const int wid = threadIdx.x >> 6;
    if (lane == 0) wsum[wid] = lsum;
    __syncthreads();
    if (threadIdx.x == 0)
        parts2[blockIdx.y * 512 + blockIdx.x] =
            (wsum[0] + wsum[1]) + (wsum[2] + wsum[3]);
}

__global__ void vq_final(const float* __restrict__ parts2, float* __restrict__ out) {
    const int lane = threadIdx.x;   /* 64 threads */
    float s = 0.0f;
    for (int i = 0; i < 2048 / 64; ++i) s += parts2[lane + 64 * i];
#pragma unroll
    for (int off = 32; off > 0; off >>= 1)
        s += __shfl_down(s, off, 64);
    if (lane == 0) {
        const float mse = s / (float)VQ_ZQ;
        out[VQ_ZQ] = mse + 0.25f * mse;
    }
}

/* ================= fallback path (round-8, validated, ~335us) ========== */
__global__ void vq_norme_fb(const float* __restrict__ emb, float* __restrict__ nEf) {
    const int c = blockIdx.x * blockDim.x + threadIdx.x;
    if (c >= VQ_N) return;
    const float* ec = emb + (c << 6);
    f32x16 zvA, zvB, zvC, zvD;
#pragma unroll
    for (int d = 0; d < 16; ++d) {
        zvA[d] = ec[d]; zvB[d] = ec[d + 16]; zvC[d] = ec[d + 32]; zvD[d] = ec[d + 48];
    }
    float s;
    NP_PAIRWISE64_SQ(s);
    nEf[c] = s;
}
__global__ __launch_bounds__(256, 4) void vq_dist_fb(
    const float* __restrict__ z, const float* __restrict__ emb,
    const float* __restrict__ nEf, float2* __restrict__ cand) {
    __shared__ float zs[VQ_D * 64];
    const int w = threadIdx.x >> 6;
    const int lane = threadIdx.x & 63;
    const int r = blockIdx.x * 64 + lane;
    const int b = r >> 12;
    const int l = r & (VQ_L - 1);
    const float* zp = z + ((size_t)b << 18) + l;
#pragma unroll
    for (int j = 0; j < 16; ++j) {
        const int d = (w << 4) + j;
        zs[d * 64 + lane] = zp[(size_t)d << 12];
    }
    __syncthreads();
    float a8[8];
#pragma unroll
    for (int j = 0; j < 8; ++j) {
        const float v = zs[j * 64 + lane];
        float s = v * v; asm volatile("" : "+v"(s)); a8[j] = s;
    }
#pragma unroll
    for (int i = 1; i < 8; ++i) {
#pragma unroll
        for (int j = 0; j < 8; ++j) {
            const float v = zs[(8 * i + j) * 64 + lane];
            float s = v * v; asm volatile("" : "+v"(s)); a8[j] += s;
        }
    }
    const float szz = ((a8[0] + a8[1]) + (a8[2] + a8[3])) + ((a8[4] + a8[5]) + (a8[6] + a8[7]));
    const int c0 = __builtin_amdgcn_readfirstlane(w) * 256;
    float best = __builtin_inff();
    int bc = c0;
    for (int t = 0; t < 256; t += 16) {
        float acc[16];
#pragma unroll
        for (int j = 0; j < 16; ++j) acc[j] = 0.0f;
#pragma unroll
        for (int kk = 0; kk < VQ_D; kk += 4) {
            const float z0 = zs[(kk + 0) * 64 + lane];
            const float z1 = zs[(kk + 1) * 64 + lane];
            const float z2 = zs[(kk + 2) * 64 + lane];
            const float z3 = zs[(kk + 3) * 64 + lane];
#pragma unroll
            for (int j = 0; j < 16; ++j) {
                const float* __restrict__ ec = emb + ((c0 + t + j) << 6) + kk;
                acc[j] = __builtin_fmaf(z0, ec[0], acc[j]);
                acc[j] = __builtin_fmaf(z1, ec[1], acc[j]);
                acc[j] = __builtin_fmaf(z2, ec[2], acc[j]);
                acc[j] = __builtin_fmaf(z3, ec[3], acc[j]);
            }
        }
#pragma unroll
        for (int j = 0; j < 16; ++j) {
            const int c = c0 + t + j;
            const float dist = (szz - 2.0f * acc[j]) + nEf[c];
            if (dist < best) { best = dist; bc = c; }
        }
    }
    cand[(size_t)w * VQ_R + r] = make_float2(best, (float)bc);
}
__global__ __launch_bounds__(MAIN_BLOCK) void vq_epilogue_fb(
    const float* __restrict__ z, const float* __restrict__ emb,
    const float2* __restrict__ cand, float* __restrict__ out,
    float* __restrict__ partials) {
    const int r = blockIdx.x * MAIN_BLOCK + threadIdx.x;
    const int b = r >> 12;
    const int l = r & (VQ_L - 1);
    float best = __builtin_inff();
    int bc = 0;
#pragma unroll
    for (int seg = 0; seg < 4; ++seg) {
        const float2 cd = cand[(size_t)seg * VQ_R + r];
        if (cd.x < best) { best = cd.x; bc = (int)cd.y; }
    }
    const float* zp = z + ((size_t)b << 18) + l;
    const float* __restrict__ eb = emb + (bc << 6);
    float lsum = 0.0f;
#pragma unroll
    for (int d = 0; d < VQ_D; ++d) {
        const float q = eb[d];
        const float zd = zp[(size_t)d << 12];
        out[((size_t)b << 18) + ((size_t)d << 12) + l] = q;
        const float df = q - zd;
        lsum = __builtin_fmaf(df, df, lsum);
    }
    out[VQ_ZQ + 1 + (size_t)r] = (float)bc;
#pragma unroll
    for (int off = 32; off > 0; off >>= 1)
        lsum += __shfl_down(lsum, off, 64);
    __shared__ float wsum[MAIN_BLOCK / 64];
    const int lane = threadIdx.x & 63;
    const int wid = threadIdx.x >> 6;
    if (lane == 0) wsum[wid] = lsum;
    __syncthreads();
    if (threadIdx.x == 0)
        partials[blockIdx.x] = (wsum[0] + wsum[1]) + (wsum[2] + wsum[3]);
}
__global__ void vq_final_fb(const float* __restrict__ partials, float* __restrict__ out) {
    if (threadIdx.x == 0 && blockIdx.x == 0) {
        float s = 0.0f;
        for (int i = 0; i < MAIN_GRID; ++i) s += partials[i];
        const float mse = s / (float)VQ_ZQ;
        out[VQ_ZQ] = mse + 0.25f * mse;
    }
}

/* ================= launch ================= */
extern "C" void kernel_launch(void* const* d_in, const int* in_sizes, int n_in,
                              void* d_out, int out_size, void* d_ws, size_t ws_size,
                              hipStream_t stream) {
    const float* z   = (const float*)d_in[0];
    const float* emb = (const float*)d_in[1];
    float* out = (float*)d_out;
    char* ws = (char*)d_ws;

    /* layout (16B-aligned). z_bf (16 MB) is dead after vq_screen; dmin /
       szz_np / ovl overlay it (memset + writes happen after the screen).
       candseg is dead after vq_pickseg; parts2 overlays it. */
    unsigned short*     z_bf   = (unsigned short*)(ws);                   /* 16777216 B */
    unsigned long long* dmin   = (unsigned long long*)(ws);               /* 1 MB  overlay */
    float*              szz_np = (float*)(ws + 1048576);                  /* 512KB overlay */
    unsigned*           ovl    = (unsigned*)(ws + 1572864);               /* 4 MB  overlay */
    unsigned short*     emb_bf = (unsigned short*)(ws + 16777216);        /*   131072 B */
    unsigned*           candsg = (unsigned*)(ws + 16908288);              /*  8388608 B */
    float*              parts2 = (float*)(ws + 16908288);                 /* 8 KB overlay */
    unsigned short*     segcnt = (unsigned short*)(ws + 25296896);        /*  1048576 B */
    float*              mrg    = (float*)(ws + 26345472);                 /*   524288 B */
    float*              nE     = (float*)(ws + 26869760);                 /*     4096 B */
    unsigned*           nEmax  = (unsigned*)(ws + 26875904);              /*        4 B */
    unsigned*           ovcnt  = (unsigned*)(ws + 26875908);              /*        4 B */
    const size_t need = 26875968;  /* same footprint as validated R17-R21 */

    if (ws_size >= need) {
        hipMemsetAsync(nEmax, 0, 8, stream);           /* nEmax, ovcnt */
        vq_prep_emb<<<dim3(4), dim3(256), 0, stream>>>(emb, nE, emb_bf, nEmax);
        vq_prep_z<<<dim3(512), dim3(256), 0, stream>>>(z, nEmax, z_bf, mrg);
        vq_screen<<<dim3(VQ_R / (64 * RT), NSEG), dim3(256), 0, stream>>>(
            z_bf, emb_bf, nE, mrg, segcnt, candsg);
        hipMemsetAsync(dmin, 0xFF, (size_t)VQ_R * 8, stream);  /* after screen */
        vq_szz<<<dim3(512), dim3(256), 0, stream>>>(z, szz_np);
        vq_pickseg<<<dim3(512, NSEG), dim3(256), 0, stream>>>(
            z, emb, nE, szz_np, segcnt, candsg, dmin, ovl, ovcnt);
        vq_overflow<<<dim3(OV_WAVES / 4), dim3(256), 0, stream>>>(
            z, emb, nE, szz_np, ovl, ovcnt, dmin);
        vq_write<<<dim3(512, 4), dim3(256), 0, stream>>>(z, emb, dmin, out, parts2);
        vq_final<<<dim3(1), dim3(64), 0, stream>>>(parts2, out);
    } else {
        /* validated round-8 fallback (~4.2 MB ws) */
        float* nEf = (float*)ws;
        float* partials = nEf + VQ_N;
        float2* cand = (float2*)(partials + MAIN_GRID);
        vq_norme_fb<<<dim3(4), dim3(256), 0, stream>>>(emb, nEf);
        vq_dist_fb<<<dim3(VQ_R / 64), dim3(256), 0, stream>>>(z, emb, nEf, cand);
        vq_epilogue_fb<<<dim3(MAIN_GRID), dim3(MAIN_BLOCK), 0, stream>>>(z, emb, cand, out, partials);
        vq_final_fb<<<dim3(1), dim3(64), 0, stream>>>(partials, out);
    }
}